// Round 1
// baseline (109.565 us; speedup 1.0000x reference)
//
#include <hip/hip_runtime.h>

#define MARGIN 0.2f
#define EPS 1e-8f

__global__ __launch_bounds__(256) void triplet_loss_kernel(
    const float* __restrict__ batch,
    const int* __restrict__ labels,
    const int* __restrict__ triplets,
    const float* __restrict__ beta,
    float* __restrict__ acc,   // acc[0]=total, acc[1]=count
    int T)
{
    int t = blockIdx.x * blockDim.x + threadIdx.x;
    float loss = 0.f, cnt = 0.f;
    if (t < T) {
        int ai = triplets[3 * t + 0];
        int pi = triplets[3 * t + 1];
        int ni = triplets[3 * t + 2];
        const float4* __restrict__ a = (const float4*)(batch + (size_t)ai * 128);
        const float4* __restrict__ p = (const float4*)(batch + (size_t)pi * 128);
        const float4* __restrict__ n = (const float4*)(batch + (size_t)ni * 128);
        float sap = 0.f, san = 0.f;
        #pragma unroll 8
        for (int i = 0; i < 32; ++i) {
            float4 av = a[i];
            float4 pv = p[i];
            float4 nv = n[i];
            float d;
            d = av.x - pv.x; sap += d * d;
            d = av.y - pv.y; sap += d * d;
            d = av.z - pv.z; sap += d * d;
            d = av.w - pv.w; sap += d * d;
            d = av.x - nv.x; san += d * d;
            d = av.y - nv.y; san += d * d;
            d = av.z - nv.z; san += d * d;
            d = av.w - nv.w; san += d * d;
        }
        float d_ap = sqrtf(sap + EPS);
        float d_an = sqrtf(san + EPS);
        float b = beta[labels[ai]];
        float pos = fmaxf(d_ap - b + MARGIN, 0.f);
        float neg = fmaxf(b - d_an + MARGIN, 0.f);
        loss = pos + neg;
        cnt = (pos > 0.f ? 1.f : 0.f) + (neg > 0.f ? 1.f : 0.f);
    }

    // wave(64) reduction
    #pragma unroll
    for (int off = 32; off > 0; off >>= 1) {
        loss += __shfl_down(loss, off);
        cnt  += __shfl_down(cnt, off);
    }

    __shared__ float sl[4];
    __shared__ float sc[4];
    int wid  = threadIdx.x >> 6;
    int lane = threadIdx.x & 63;
    if (lane == 0) { sl[wid] = loss; sc[wid] = cnt; }
    __syncthreads();
    if (threadIdx.x == 0) {
        float L = sl[0] + sl[1] + sl[2] + sl[3];
        float C = sc[0] + sc[1] + sc[2] + sc[3];
        atomicAdd(&acc[0], L);
        atomicAdd(&acc[1], C);
    }
}

__global__ void triplet_finalize_kernel(const float* __restrict__ acc,
                                        float* __restrict__ out)
{
    float total = acc[0];
    float count = acc[1];
    out[0] = (count > 0.f) ? (total / fmaxf(count, 1.f)) : total;
}

extern "C" void kernel_launch(void* const* d_in, const int* in_sizes, int n_in,
                              void* d_out, int out_size, void* d_ws, size_t ws_size,
                              hipStream_t stream) {
    const float* batch    = (const float*)d_in[0];
    const int*   labels   = (const int*)d_in[1];
    const int*   triplets = (const int*)d_in[2];
    const float* beta     = (const float*)d_in[3];
    float* out = (float*)d_out;
    float* acc = (float*)d_ws;

    int T = in_sizes[2] / 3;

    hipMemsetAsync(acc, 0, 2 * sizeof(float), stream);

    int block = 256;
    int grid = (T + block - 1) / block;
    triplet_loss_kernel<<<grid, block, 0, stream>>>(batch, labels, triplets, beta, acc, T);
    triplet_finalize_kernel<<<1, 1, 0, stream>>>(acc, out);
}

// Round 2
// 54.215 us; speedup vs baseline: 2.0209x; 2.0209x over previous
//
#include <hip/hip_runtime.h>

#define MARGIN 0.2f
#define EPS 1e-8f
#define GRID_BLOCKS 2048

// 32 lanes cooperate on one triplet: lane fi (0..31) loads float4 #fi of each
// 128-float row => every VMEM instruction covers 2 rows x 512B contiguous.
__global__ __launch_bounds__(256) void triplet_loss_kernel(
    const float* __restrict__ batch,
    const int* __restrict__ labels,
    const int* __restrict__ triplets,
    const float* __restrict__ beta,
    float* __restrict__ partial,   // [gridDim.x * 2]
    int T)
{
    const int lane = threadIdx.x & 63;
    const int wid  = threadIdx.x >> 6;   // wave in block: 0..3
    const int sub  = lane >> 5;          // triplet slot within wave: 0..1
    const int fi   = lane & 31;          // float4 index within row

    float loss = 0.f, cnt = 0.f;

    for (int base = blockIdx.x * 8; base < T; base += gridDim.x * 8) {
        int t = base + wid * 2 + sub;
        if (t < T) {
            int ai = triplets[3 * t + 0];
            int pi = triplets[3 * t + 1];
            int ni = triplets[3 * t + 2];
            int lab = 0;
            if (fi == 0) lab = labels[ai];     // issue early; only group leader needs it
            const float4 av = *(const float4*)(batch + ((size_t)ai << 7) + (fi << 2));
            const float4 pv = *(const float4*)(batch + ((size_t)pi << 7) + (fi << 2));
            const float4 nv = *(const float4*)(batch + ((size_t)ni << 7) + (fi << 2));
            float b = 0.f;
            if (fi == 0) b = beta[lab];
            float d, sap, san;
            d = av.x - pv.x; sap  = d * d;
            d = av.y - pv.y; sap += d * d;
            d = av.z - pv.z; sap += d * d;
            d = av.w - pv.w; sap += d * d;
            d = av.x - nv.x; san  = d * d;
            d = av.y - nv.y; san += d * d;
            d = av.z - nv.z; san += d * d;
            d = av.w - nv.w; san += d * d;
            // reduce across the 32-lane group (xor masks <=16 stay in-group)
            #pragma unroll
            for (int off = 16; off >= 1; off >>= 1) {
                sap += __shfl_xor(sap, off);
                san += __shfl_xor(san, off);
            }
            if (fi == 0) {
                float d_ap = sqrtf(sap + EPS);
                float d_an = sqrtf(san + EPS);
                float pos = fmaxf(d_ap - b + MARGIN, 0.f);
                float neg = fmaxf(b - d_an + MARGIN, 0.f);
                loss += pos + neg;
                cnt  += (pos > 0.f ? 1.f : 0.f) + (neg > 0.f ? 1.f : 0.f);
            }
        }
    }

    // full wave reduce (only lanes 0 and 32 hold nonzero, cost is trivial)
    #pragma unroll
    for (int off = 32; off >= 1; off >>= 1) {
        loss += __shfl_down(loss, off);
        cnt  += __shfl_down(cnt, off);
    }
    __shared__ float sl[4], sc[4];
    if (lane == 0) { sl[wid] = loss; sc[wid] = cnt; }
    __syncthreads();
    if (threadIdx.x == 0) {
        partial[blockIdx.x * 2 + 0] = sl[0] + sl[1] + sl[2] + sl[3];
        partial[blockIdx.x * 2 + 1] = sc[0] + sc[1] + sc[2] + sc[3];
    }
}

__global__ __launch_bounds__(1024) void triplet_finalize_kernel(
    const float* __restrict__ partial, float* __restrict__ out, int nblocks)
{
    float L = 0.f, C = 0.f;
    for (int i = threadIdx.x; i < nblocks; i += blockDim.x) {
        L += partial[2 * i + 0];
        C += partial[2 * i + 1];
    }
    #pragma unroll
    for (int off = 32; off >= 1; off >>= 1) {
        L += __shfl_down(L, off);
        C += __shfl_down(C, off);
    }
    __shared__ float sl[16], sc[16];
    int wid  = threadIdx.x >> 6;
    int lane = threadIdx.x & 63;
    int nw   = blockDim.x >> 6;
    if (lane == 0) { sl[wid] = L; sc[wid] = C; }
    __syncthreads();
    if (threadIdx.x == 0) {
        float Lt = 0.f, Ct = 0.f;
        for (int i = 0; i < nw; ++i) { Lt += sl[i]; Ct += sc[i]; }
        out[0] = (Ct > 0.f) ? (Lt / fmaxf(Ct, 1.f)) : Lt;
    }
}

extern "C" void kernel_launch(void* const* d_in, const int* in_sizes, int n_in,
                              void* d_out, int out_size, void* d_ws, size_t ws_size,
                              hipStream_t stream) {
    const float* batch    = (const float*)d_in[0];
    const int*   labels   = (const int*)d_in[1];
    const int*   triplets = (const int*)d_in[2];
    const float* beta     = (const float*)d_in[3];
    float* out     = (float*)d_out;
    float* partial = (float*)d_ws;

    int T = in_sizes[2] / 3;
    int grid = GRID_BLOCKS;
    int groups = (T + 7) / 8;
    if (grid > groups) grid = groups;

    triplet_loss_kernel<<<grid, 256, 0, stream>>>(batch, labels, triplets, beta, partial, T);
    triplet_finalize_kernel<<<1, 1024, 0, stream>>>(partial, out, grid);
}

// Round 3
// 37.423 us; speedup vs baseline: 2.9277x; 1.4487x over previous
//
#include <hip/hip_runtime.h>

#define MARGIN 0.2f
#define EPS 1e-8f
#define GRID_BLOCKS 2048

// 8 lanes cooperate on one triplet (8 triplets per wave64).
// Lane fi (0..7) loads float4 #fi, #fi+8, #fi+16, #fi+24 of each 128-float row:
// per load instruction an 8-lane group covers 128B contiguous; 4 loads per row
// use immediate offsets off one base address.
// After the 3-step butterfly all 8 lanes hold the full sums, so ALL lanes
// compute the hinge and accumulate (8x duplicated, divided out in finalize) --
// no leader-lane branches, no exec-mask churn in the hot loop.
__global__ __launch_bounds__(256) void triplet_loss_kernel(
    const float* __restrict__ batch,
    const int* __restrict__ labels,
    const int* __restrict__ triplets,
    const float* __restrict__ beta,
    float* __restrict__ partial,   // [gridDim.x * 2], 8x-scaled sums
    int T)
{
    const int lane = threadIdx.x & 63;
    const int wid  = threadIdx.x >> 6;   // wave in block: 0..3
    const int sub  = lane >> 3;          // triplet slot within wave: 0..7
    const int fi   = lane & 7;           // float4 base index within row

    float loss = 0.f, cnt = 0.f;

    for (int base = blockIdx.x * 32; base < T; base += gridDim.x * 32) {
        int t = base + wid * 8 + sub;
        if (t < T) {
            int ai = triplets[3 * t + 0];
            int pi = triplets[3 * t + 1];
            int ni = triplets[3 * t + 2];
            // issue the dependent beta chain early; hides under row loads
            float b = beta[labels[ai]];
            const float4* __restrict__ arow = (const float4*)(batch + ((size_t)ai << 7));
            const float4* __restrict__ prow = (const float4*)(batch + ((size_t)pi << 7));
            const float4* __restrict__ nrow = (const float4*)(batch + ((size_t)ni << 7));
            float sap = 0.f, san = 0.f;
            #pragma unroll
            for (int k = 0; k < 4; ++k) {
                float4 av = arow[fi + 8 * k];
                float4 pv = prow[fi + 8 * k];
                float4 nv = nrow[fi + 8 * k];
                float d;
                d = av.x - pv.x; sap += d * d;
                d = av.y - pv.y; sap += d * d;
                d = av.z - pv.z; sap += d * d;
                d = av.w - pv.w; sap += d * d;
                d = av.x - nv.x; san += d * d;
                d = av.y - nv.y; san += d * d;
                d = av.z - nv.z; san += d * d;
                d = av.w - nv.w; san += d * d;
            }
            // butterfly across the 8-lane group
            #pragma unroll
            for (int off = 4; off >= 1; off >>= 1) {
                sap += __shfl_xor(sap, off);
                san += __shfl_xor(san, off);
            }
            float d_ap = sqrtf(sap + EPS);
            float d_an = sqrtf(san + EPS);
            float pos = fmaxf(d_ap - b + MARGIN, 0.f);
            float neg = fmaxf(b - d_an + MARGIN, 0.f);
            loss += pos + neg;                                        // 8x duplicated
            cnt  += (pos > 0.f ? 1.f : 0.f) + (neg > 0.f ? 1.f : 0.f); // 8x duplicated
        }
    }

    // full wave reduce, then block reduce (once per kernel, cost trivial)
    #pragma unroll
    for (int off = 32; off >= 1; off >>= 1) {
        loss += __shfl_down(loss, off);
        cnt  += __shfl_down(cnt, off);
    }
    __shared__ float sl[4], sc[4];
    if (lane == 0) { sl[wid] = loss; sc[wid] = cnt; }
    __syncthreads();
    if (threadIdx.x == 0) {
        partial[blockIdx.x * 2 + 0] = sl[0] + sl[1] + sl[2] + sl[3];
        partial[blockIdx.x * 2 + 1] = sc[0] + sc[1] + sc[2] + sc[3];
    }
}

__global__ __launch_bounds__(1024) void triplet_finalize_kernel(
    const float* __restrict__ partial, float* __restrict__ out, int nblocks)
{
    float L = 0.f, C = 0.f;
    for (int i = threadIdx.x; i < nblocks; i += blockDim.x) {
        L += partial[2 * i + 0];
        C += partial[2 * i + 1];
    }
    #pragma unroll
    for (int off = 32; off >= 1; off >>= 1) {
        L += __shfl_down(L, off);
        C += __shfl_down(C, off);
    }
    __shared__ float sl[16], sc[16];
    int wid  = threadIdx.x >> 6;
    int lane = threadIdx.x & 63;
    int nw   = blockDim.x >> 6;
    if (lane == 0) { sl[wid] = L; sc[wid] = C; }
    __syncthreads();
    if (threadIdx.x == 0) {
        float Lt = 0.f, Ct = 0.f;
        for (int i = 0; i < nw; ++i) { Lt += sl[i]; Ct += sc[i]; }
        Lt *= 0.125f;   // undo 8x duplication
        Ct *= 0.125f;
        out[0] = (Ct > 0.f) ? (Lt / fmaxf(Ct, 1.f)) : Lt;
    }
}

extern "C" void kernel_launch(void* const* d_in, const int* in_sizes, int n_in,
                              void* d_out, int out_size, void* d_ws, size_t ws_size,
                              hipStream_t stream) {
    const float* batch    = (const float*)d_in[0];
    const int*   labels   = (const int*)d_in[1];
    const int*   triplets = (const int*)d_in[2];
    const float* beta     = (const float*)d_in[3];
    float* out     = (float*)d_out;
    float* partial = (float*)d_ws;

    int T = in_sizes[2] / 3;
    int grid = GRID_BLOCKS;
    int groups = (T + 31) / 32;
    if (grid > groups) grid = groups;

    triplet_loss_kernel<<<grid, 256, 0, stream>>>(batch, labels, triplets, beta, partial, T);
    triplet_finalize_kernel<<<1, 1024, 0, stream>>>(partial, out, grid);
}

// Round 4
// 30.972 us; speedup vs baseline: 3.5375x; 1.2083x over previous
//
#include <hip/hip_runtime.h>

#define MARGIN 0.2f
#define EPS 1e-8f
#define GRID_BLOCKS 2048

typedef _Float16 h2 __attribute__((ext_vector_type(2)));
typedef _Float16 h8 __attribute__((ext_vector_type(8)));
union H8 { h8 v; h2 p[4]; };

// ---- fp16 path ------------------------------------------------------------

__global__ __launch_bounds__(256) void convert_f32_to_f16_kernel(
    const float* __restrict__ in, _Float16* __restrict__ out, int n4)
{
    int i = blockIdx.x * blockDim.x + threadIdx.x;
    if (i < n4) {
        float4 f = *(const float4*)(in + 4 * (size_t)i);
        h2 lo, hi;
        lo.x = (_Float16)f.x; lo.y = (_Float16)f.y;
        hi.x = (_Float16)f.z; hi.y = (_Float16)f.w;
        *(h2*)(out + 4 * (size_t)i)     = lo;
        *(h2*)(out + 4 * (size_t)i + 2) = hi;
    }
}

// 4 lanes per triplet (16 triplets per wave64). Row = 128 fp16 = 256B = 16 h8
// chunks; lane fi takes chunks fi+4k (k=0..3): each 4-lane group covers 64B
// contiguous per load. Diffs via packed fp16 sub, dot via v_dot2_f32_f16
// (full-precision products, f32 accumulate). After the 2-step butterfly all
// 4 lanes hold the sums; all compute the hinge (4x dup, scaled out later).
__global__ __launch_bounds__(256) void triplet_loss_f16_kernel(
    const _Float16* __restrict__ batch16,
    const int* __restrict__ labels,
    const int* __restrict__ triplets,
    const float* __restrict__ beta,
    float* __restrict__ partial,   // [gridDim.x * 2], 4x-scaled sums
    int T)
{
    const int lane = threadIdx.x & 63;
    const int wid  = threadIdx.x >> 6;   // wave in block: 0..3
    const int sub  = lane >> 2;          // triplet slot in wave: 0..15
    const int fi   = lane & 3;           // h8-chunk base within row

    float loss = 0.f, cnt = 0.f;

    for (int base = blockIdx.x * 64; base < T; base += gridDim.x * 64) {
        int t = base + wid * 16 + sub;
        if (t < T) {
            int ai = triplets[3 * t + 0];
            int pi = triplets[3 * t + 1];
            int ni = triplets[3 * t + 2];
            float b = beta[labels[ai]];   // dependent chain issued early
            const h8* __restrict__ arow = (const h8*)(batch16 + ((size_t)ai << 7));
            const h8* __restrict__ prow = (const h8*)(batch16 + ((size_t)pi << 7));
            const h8* __restrict__ nrow = (const h8*)(batch16 + ((size_t)ni << 7));
            float sap = 0.f, san = 0.f;
            #pragma unroll
            for (int k = 0; k < 4; ++k) {
                H8 a, p, n, dp, dn;
                a.v = arow[fi + 4 * k];
                p.v = prow[fi + 4 * k];
                n.v = nrow[fi + 4 * k];
                dp.v = a.v - p.v;
                dn.v = a.v - n.v;
                #pragma unroll
                for (int j = 0; j < 4; ++j) {
                    sap = __builtin_amdgcn_fdot2(dp.p[j], dp.p[j], sap, false);
                    san = __builtin_amdgcn_fdot2(dn.p[j], dn.p[j], san, false);
                }
            }
            #pragma unroll
            for (int off = 2; off >= 1; off >>= 1) {
                sap += __shfl_xor(sap, off);
                san += __shfl_xor(san, off);
            }
            float d_ap = sqrtf(sap + EPS);
            float d_an = sqrtf(san + EPS);
            float pos = fmaxf(d_ap - b + MARGIN, 0.f);
            float neg = fmaxf(b - d_an + MARGIN, 0.f);
            loss += pos + neg;                                         // 4x dup
            cnt  += (pos > 0.f ? 1.f : 0.f) + (neg > 0.f ? 1.f : 0.f); // 4x dup
        }
    }

    #pragma unroll
    for (int off = 32; off >= 1; off >>= 1) {
        loss += __shfl_down(loss, off);
        cnt  += __shfl_down(cnt, off);
    }
    __shared__ float sl[4], sc[4];
    if (lane == 0) { sl[wid] = loss; sc[wid] = cnt; }
    __syncthreads();
    if (threadIdx.x == 0) {
        partial[blockIdx.x * 2 + 0] = sl[0] + sl[1] + sl[2] + sl[3];
        partial[blockIdx.x * 2 + 1] = sc[0] + sc[1] + sc[2] + sc[3];
    }
}

// ---- fp32 fallback (round-3 kernel, known-good) ---------------------------

__global__ __launch_bounds__(256) void triplet_loss_f32_kernel(
    const float* __restrict__ batch,
    const int* __restrict__ labels,
    const int* __restrict__ triplets,
    const float* __restrict__ beta,
    float* __restrict__ partial,   // [gridDim.x * 2], 8x-scaled sums
    int T)
{
    const int lane = threadIdx.x & 63;
    const int wid  = threadIdx.x >> 6;
    const int sub  = lane >> 3;
    const int fi   = lane & 7;

    float loss = 0.f, cnt = 0.f;

    for (int base = blockIdx.x * 32; base < T; base += gridDim.x * 32) {
        int t = base + wid * 8 + sub;
        if (t < T) {
            int ai = triplets[3 * t + 0];
            int pi = triplets[3 * t + 1];
            int ni = triplets[3 * t + 2];
            float b = beta[labels[ai]];
            const float4* __restrict__ arow = (const float4*)(batch + ((size_t)ai << 7));
            const float4* __restrict__ prow = (const float4*)(batch + ((size_t)pi << 7));
            const float4* __restrict__ nrow = (const float4*)(batch + ((size_t)ni << 7));
            float sap = 0.f, san = 0.f;
            #pragma unroll
            for (int k = 0; k < 4; ++k) {
                float4 av = arow[fi + 8 * k];
                float4 pv = prow[fi + 8 * k];
                float4 nv = nrow[fi + 8 * k];
                float d;
                d = av.x - pv.x; sap += d * d;
                d = av.y - pv.y; sap += d * d;
                d = av.z - pv.z; sap += d * d;
                d = av.w - pv.w; sap += d * d;
                d = av.x - nv.x; san += d * d;
                d = av.y - nv.y; san += d * d;
                d = av.z - nv.z; san += d * d;
                d = av.w - nv.w; san += d * d;
            }
            #pragma unroll
            for (int off = 4; off >= 1; off >>= 1) {
                sap += __shfl_xor(sap, off);
                san += __shfl_xor(san, off);
            }
            float d_ap = sqrtf(sap + EPS);
            float d_an = sqrtf(san + EPS);
            float pos = fmaxf(d_ap - b + MARGIN, 0.f);
            float neg = fmaxf(b - d_an + MARGIN, 0.f);
            loss += pos + neg;
            cnt  += (pos > 0.f ? 1.f : 0.f) + (neg > 0.f ? 1.f : 0.f);
        }
    }

    #pragma unroll
    for (int off = 32; off >= 1; off >>= 1) {
        loss += __shfl_down(loss, off);
        cnt  += __shfl_down(cnt, off);
    }
    __shared__ float sl[4], sc[4];
    if (lane == 0) { sl[wid] = loss; sc[wid] = cnt; }
    __syncthreads();
    if (threadIdx.x == 0) {
        partial[blockIdx.x * 2 + 0] = sl[0] + sl[1] + sl[2] + sl[3];
        partial[blockIdx.x * 2 + 1] = sc[0] + sc[1] + sc[2] + sc[3];
    }
}

// ---- finalize --------------------------------------------------------------

__global__ __launch_bounds__(1024) void triplet_finalize_kernel(
    const float* __restrict__ partial, float* __restrict__ out, int nblocks,
    float scale)
{
    float L = 0.f, C = 0.f;
    for (int i = threadIdx.x; i < nblocks; i += blockDim.x) {
        L += partial[2 * i + 0];
        C += partial[2 * i + 1];
    }
    #pragma unroll
    for (int off = 32; off >= 1; off >>= 1) {
        L += __shfl_down(L, off);
        C += __shfl_down(C, off);
    }
    __shared__ float sl[16], sc[16];
    int wid  = threadIdx.x >> 6;
    int lane = threadIdx.x & 63;
    int nw   = blockDim.x >> 6;
    if (lane == 0) { sl[wid] = L; sc[wid] = C; }
    __syncthreads();
    if (threadIdx.x == 0) {
        float Lt = 0.f, Ct = 0.f;
        for (int i = 0; i < nw; ++i) { Lt += sl[i]; Ct += sc[i]; }
        Lt *= scale;
        Ct *= scale;
        out[0] = (Ct > 0.f) ? (Lt / fmaxf(Ct, 1.f)) : Lt;
    }
}

extern "C" void kernel_launch(void* const* d_in, const int* in_sizes, int n_in,
                              void* d_out, int out_size, void* d_ws, size_t ws_size,
                              hipStream_t stream) {
    const float* batch    = (const float*)d_in[0];
    const int*   labels   = (const int*)d_in[1];
    const int*   triplets = (const int*)d_in[2];
    const float* beta     = (const float*)d_in[3];
    float* out = (float*)d_out;

    int nbatch = in_sizes[0];          // 4096*128
    int T = in_sizes[2] / 3;

    size_t f16_bytes = (size_t)nbatch * sizeof(_Float16);
    size_t need = f16_bytes + (size_t)GRID_BLOCKS * 2 * sizeof(float);

    if (ws_size >= need) {
        _Float16* batch16 = (_Float16*)d_ws;
        float* partial = (float*)((char*)d_ws + f16_bytes);

        int n4 = nbatch / 4;
        convert_f32_to_f16_kernel<<<(n4 + 255) / 256, 256, 0, stream>>>(batch, batch16, n4);

        int grid = GRID_BLOCKS;
        int groups = (T + 63) / 64;
        if (grid > groups) grid = groups;
        triplet_loss_f16_kernel<<<grid, 256, 0, stream>>>(batch16, labels, triplets, beta, partial, T);
        triplet_finalize_kernel<<<1, 1024, 0, stream>>>(partial, out, grid, 0.25f);
    } else {
        float* partial = (float*)d_ws;
        int grid = GRID_BLOCKS;
        int groups = (T + 31) / 32;
        if (grid > groups) grid = groups;
        triplet_loss_f32_kernel<<<grid, 256, 0, stream>>>(batch, labels, triplets, beta, partial, T);
        triplet_finalize_kernel<<<1, 1024, 0, stream>>>(partial, out, grid, 0.125f);
    }
}